// Round 3
// baseline (1658.823 us; speedup 1.0000x reference)
//
#include <hip/hip_runtime.h>
#include <cstdint>
#include <math.h>

#define TW 64
#define TH 16
#define CAPMAX 16384
#define KDET 100

// ---------------------------------------------------------------------------
// Kernel 1: replicate the reference's float32 softmax bitwise, 3x3 NMS in
// f32-conf space, candidate compaction.
//   m  = fmax(x0, x1)                (IEEE, matches np)
//   ui = (float)exp((double)(xi-m))  (correctly-rounded f32 exp; exp(0)=1)
//   s  = u0 + u1; conf = u1 / s      (IEEE add/div, match np bitwise)
// The f32 rounding of `1 + u0` collapses near-equal confs into exact ties;
// ordering must therefore be done on conf_f32 (ties -> lower index), NOT on
// the higher-precision logit difference.
// conf in (0,1) => its bit pattern as unsigned is order-preserving.
// Key = (conf_bits << 32) | (0xFFFFFFFF - index).
// ---------------------------------------------------------------------------
__global__ __launch_bounds__(256) void nms_kernel(
    const float* __restrict__ fm,          // (64, 2, H, W)
    uint32_t* __restrict__ counters,       // 128 counters
    int counter_base,                      // 0 = player, 64 = ball
    unsigned long long* __restrict__ cand, // 128 * cap keys
    int cap, int H, int W, int tiles_x, int tiles_y)
{
    const int tpi = tiles_x * tiles_y;
    const int img = blockIdx.x / tpi;
    const int t   = blockIdx.x % tpi;
    const int tx = t % tiles_x, ty = t / tiles_x;

    const size_t hw = (size_t)H * W;
    const float* c0 = fm + (size_t)img * 2 * hw;
    const float* c1 = c0 + hw;

    __shared__ float sc[TH + 2][TW + 2];

    const int x0 = tx * TW - 1;
    const int y0 = ty * TH - 1;

    // halo load: compute f32 conf on the fly; OOB = -inf (SAME pad w/ -inf)
    for (int i = threadIdx.x; i < (TH + 2) * (TW + 2); i += 256) {
        int lx = i % (TW + 2), ly = i / (TW + 2);
        int gx = x0 + lx, gy = y0 + ly;
        float conf = -INFINITY;
        if (gx >= 0 && gx < W && gy >= 0 && gy < H) {
            int g = gy * W + gx;
            float a = c0[g], b = c1[g];
            float m  = fmaxf(a, b);
            float t0 = a - m, t1 = b - m;           // exact IEEE sub
            float u0 = (float)exp((double)t0);      // correctly-rounded exp
            float u1 = (float)exp((double)t1);      // (exp(0) == 1 exactly)
            float s  = u0 + u1;                     // IEEE add
            conf = u1 / s;                          // IEEE div
        }
        sc[ly][lx] = conf;
    }
    __syncthreads();

    for (int i = threadIdx.x; i < TH * TW; i += 256) {
        int lx = i % TW, ly = i / TW;
        int gx = tx * TW + lx, gy = ty * TH + ly;
        if (gx >= W || gy >= H) continue;
        float c = sc[ly + 1][lx + 1];
        // keep iff center == max of 3x3 window (f32-conf space, as reference)
        bool keep = (sc[ly    ][lx    ] <= c) & (sc[ly    ][lx + 1] <= c) &
                    (sc[ly    ][lx + 2] <= c) & (sc[ly + 1][lx    ] <= c) &
                    (sc[ly + 1][lx + 2] <= c) & (sc[ly + 2][lx    ] <= c) &
                    (sc[ly + 2][lx + 1] <= c) & (sc[ly + 2][lx + 2] <= c);
        if (keep) {
            uint32_t idx = (uint32_t)(gy * W + gx);
            uint32_t cb  = __float_as_uint(c);   // conf > 0 => monotone bits
            unsigned long long key =
                ((unsigned long long)cb << 32) |
                (unsigned long long)(0xFFFFFFFFu - idx);
            uint32_t slot = atomicAdd(&counters[counter_base + img], 1u);
            if (slot < (uint32_t)cap)
                cand[(size_t)(counter_base + img) * cap + slot] = key;
        }
    }
}

// ---------------------------------------------------------------------------
// Kernel 2: per-(map,image) exact top-100 via 8-pass MSB radix select over
// 64-bit keys staged in LDS, then compact + bitonic sort + decode/write.
// ---------------------------------------------------------------------------
__global__ __launch_bounds__(256) void select_kernel(
    const unsigned long long* __restrict__ cand,
    const uint32_t* __restrict__ counters,
    int cap,
    const float* __restrict__ pbbox,   // (64, 4, 68, 120)
    float* __restrict__ out)           // (64, 200, 5)
{
    const int b   = blockIdx.x;   // 0..127
    const int map = b >> 6;       // 0 = player, 1 = ball
    const int img = b & 63;

    __shared__ unsigned long long skeys[CAPMAX];   // 128 KB
    __shared__ unsigned int hist[256];
    __shared__ unsigned long long stop[128];
    __shared__ unsigned int scnt;
    __shared__ unsigned long long s_prefix;
    __shared__ unsigned int s_krem;

    unsigned craw = counters[b];
    int c = (int)(craw < (unsigned)cap ? craw : (unsigned)cap);
    const unsigned long long* my = cand + (size_t)b * cap;

    for (int i = threadIdx.x; i < c; i += 256) skeys[i] = my[i];
    if (threadIdx.x == 0) { s_prefix = 0ull; s_krem = KDET; scnt = 0u; }
    __syncthreads();

    // 8-pass MSB radix select for the KDET-th largest key
    for (int pass = 0; pass < 8; ++pass) {
        int shift = 56 - 8 * pass;
        for (int i = threadIdx.x; i < 256; i += 256) hist[i] = 0u;
        __syncthreads();
        unsigned long long pref = s_prefix;
        for (int i = threadIdx.x; i < c; i += 256) {
            unsigned long long key = skeys[i];
            bool match = (pass == 0) || ((key >> (shift + 8)) == pref);
            if (match) atomicAdd(&hist[(unsigned)(key >> shift) & 255u], 1u);
        }
        __syncthreads();
        if (threadIdx.x == 0) {
            unsigned krem = s_krem;
            unsigned cum = 0; int sel = 0;
            for (int bin = 255; bin >= 0; --bin) {
                unsigned h = hist[bin];
                if (cum + h >= krem) { sel = bin; s_krem = krem - cum; break; }
                cum += h;
            }
            s_prefix = (s_prefix << 8) | (unsigned long long)(unsigned)sel;
        }
        __syncthreads();
    }
    unsigned long long kth = s_prefix;

    // compact keys >= kth; keys are unique (index bits) -> exactly KDET
    for (int i = threadIdx.x; i < c; i += 256) {
        unsigned long long key = skeys[i];
        if (key >= kth) {
            unsigned p = atomicAdd(&scnt, 1u);
            if (p < 128u) stop[p] = key;
        }
    }
    __syncthreads();
    unsigned cnt = scnt;
    for (int i = threadIdx.x; i < 128; i += 256)
        if ((unsigned)i >= cnt) stop[i] = 0ull;

    // bitonic sort ascending, n = 128
    for (int k2 = 2; k2 <= 128; k2 <<= 1) {
        for (int j = k2 >> 1; j > 0; j >>= 1) {
            __syncthreads();
            if (threadIdx.x < 128) {
                int i = threadIdx.x, ixj = i ^ j;
                if (ixj > i) {
                    unsigned long long a = stop[i], bb = stop[ixj];
                    bool up = ((i & k2) == 0);
                    if ((up && a > bb) || (!up && a < bb)) { stop[i] = bb; stop[ixj] = a; }
                }
            }
        }
    }
    __syncthreads();

    // decode + write: rank r takes stop[127 - r] (descending)
    int r = threadIdx.x;
    if (r < KDET) {
        unsigned long long key = stop[127 - r];
        float* o = out + ((size_t)img * 200 + (map ? (100 + r) : r)) * 5;
        if (key == 0ull) {   // cannot happen with this data; safe fallback
            o[0] = 0.f; o[1] = 0.f; o[2] = 0.f; o[3] = 0.f; o[4] = 0.f;
        } else {
            float val = __uint_as_float((unsigned)(key >> 32));  // ref's conf
            unsigned idx = 0xFFFFFFFFu - (unsigned)(key & 0xFFFFFFFFull);

            int W  = map ? 480 : 120;
            float ds   = map ? 4.0f : 16.0f;
            float half = map ? 1.5f : 7.5f;
            int ix = (int)(idx % (unsigned)W), iy = (int)(idx / (unsigned)W);
            float xc = (float)ix * ds + half;
            float yc = (float)iy * ds + half;

            float t0, t1, t2, t3;
            if (map == 0) {
                const float* bb = pbbox + (size_t)img * 4 * 8160;
                t0 = bb[idx]            * 1920.0f;   // w*ds = 120*16
                t1 = bb[8160 + idx]     * 1088.0f;   // h*ds = 68*16
                t2 = bb[2 * 8160 + idx] * 1920.0f;
                t3 = bb[3 * 8160 + idx] * 1088.0f;
            } else {
                t0 = 0.0f; t1 = 0.0f; t2 = 20.0f; t3 = 20.0f;
            }
            float bx = xc + t0, by = yc + t1;
            o[0] = bx - 0.5f * t2;
            o[1] = by - 0.5f * t3;
            o[2] = bx + 0.5f * t2;
            o[3] = by + 0.5f * t3;
            o[4] = val;
        }
    }
}

extern "C" void kernel_launch(void* const* d_in, const int* in_sizes, int n_in,
                              void* d_out, int out_size, void* d_ws, size_t ws_size,
                              hipStream_t stream) {
    const float* pfm = (const float*)d_in[0];  // (64,2,68,120)
    const float* pbb = (const float*)d_in[1];  // (64,4,68,120)
    const float* bfm = (const float*)d_in[2];  // (64,2,272,480)
    float* out = (float*)d_out;                // (64,200,5)

    uint32_t* counters = (uint32_t*)d_ws;                                  // 128 * u32
    unsigned long long* cand = (unsigned long long*)((char*)d_ws + 512);

    int cap = CAPMAX;
    size_t need = 512 + (size_t)128 * (size_t)cap * 8;
    if (ws_size < need) {  // defensive; deterministic across calls
        cap = (int)((ws_size > 512 ? (ws_size - 512) : 0) / (128 * 8));
        if (cap > CAPMAX) cap = CAPMAX;
        if (cap < 1) cap = 1;
    }

    hipMemsetAsync(d_ws, 0, 512, stream);

    {   // player: H=68 W=120
        int tiles_x = (120 + TW - 1) / TW;   // 2
        int tiles_y = (68  + TH - 1) / TH;   // 5
        nms_kernel<<<64 * tiles_x * tiles_y, 256, 0, stream>>>(
            pfm, counters, 0, cand, cap, 68, 120, tiles_x, tiles_y);
    }
    {   // ball: H=272 W=480
        int tiles_x = (480 + TW - 1) / TW;   // 8
        int tiles_y = (272 + TH - 1) / TH;   // 17
        nms_kernel<<<64 * tiles_x * tiles_y, 256, 0, stream>>>(
            bfm, counters, 64, cand, cap, 272, 480, tiles_x, tiles_y);
    }
    select_kernel<<<128, 256, 0, stream>>>(cand, counters, cap, pbb, out);
}

// Round 4
// 355.394 us; speedup vs baseline: 4.6676x; 4.6676x over previous
//
#include <hip/hip_runtime.h>
#include <cstdint>
#include <math.h>

#define TW 64
#define TH 16
#define CAPMAX 16384
#define KDET 100

// ---------------------------------------------------------------------------
// Kernel 1: replicate the reference's float32 softmax bitwise, 3x3 NMS in
// f32-conf space, block-aggregated candidate compaction.
//   m = max(x0,x1); one of exp args is 0 -> exp(0)=1 exactly, so only ONE
//   correctly-rounded exp per pixel:
//     t = min - max; u = (float)exp((double)t); s = u + 1; conf = u/s or 1/s
//   (bitwise identical to np: e0+e1 with one ei==1, IEEE add commutative)
// Ordering must be on conf_f32 (f32 rounding creates exact ties that the
// reference's top_k breaks by lower index) -> key = (conf_bits<<32)|(~idx).
// Global atomics: ONE per block (slot-range reservation), not one per keep —
// per-candidate same-address RMWs were the 1.4 ms serialization in round 3.
// ---------------------------------------------------------------------------
__global__ __launch_bounds__(256) void nms_kernel(
    const float* __restrict__ fm,          // (64, 2, H, W)
    uint32_t* __restrict__ counters,       // 128 counters
    int counter_base,                      // 0 = player, 64 = ball
    unsigned long long* __restrict__ cand, // 128 * cap keys
    int cap, int H, int W, int tiles_x, int tiles_y)
{
    const int tpi = tiles_x * tiles_y;
    const int img = blockIdx.x / tpi;
    const int t   = blockIdx.x % tpi;
    const int tx = t % tiles_x, ty = t / tiles_x;

    const size_t hw = (size_t)H * W;
    const float* c0 = fm + (size_t)img * 2 * hw;
    const float* c1 = c0 + hw;

    __shared__ float sc[TH + 2][TW + 2];
    __shared__ unsigned long long s_keys[TH * TW];
    __shared__ unsigned int s_cnt;
    __shared__ unsigned int s_base;

    if (threadIdx.x == 0) s_cnt = 0u;

    const int x0 = tx * TW - 1;
    const int y0 = ty * TH - 1;

    // halo load: compute f32 conf on the fly; OOB = -inf (SAME pad w/ -inf)
    for (int i = threadIdx.x; i < (TH + 2) * (TW + 2); i += 256) {
        int lx = i % (TW + 2), ly = i / (TW + 2);
        int gx = x0 + lx, gy = y0 + ly;
        float conf = -INFINITY;
        if (gx >= 0 && gx < W && gy >= 0 && gy < H) {
            int g = gy * W + gx;
            float a = c0[g], b = c1[g];
            float tm = (a > b) ? (b - a) : (a - b);   // min - max (<= 0)
            float u  = (float)exp((double)tm);        // correctly-rounded f32
            float s  = u + 1.0f;                      // == e0 + e1 (one is 1)
            conf = (a > b) ? (u / s) : (1.0f / s);    // channel-1 prob
        }
        sc[ly][lx] = conf;
    }
    __syncthreads();

    for (int i = threadIdx.x; i < TH * TW; i += 256) {
        int lx = i % TW, ly = i / TW;
        int gx = tx * TW + lx, gy = ty * TH + ly;
        if (gx >= W || gy >= H) continue;
        float c = sc[ly + 1][lx + 1];
        // keep iff center == max of 3x3 window (f32-conf space, as reference)
        bool keep = (sc[ly    ][lx    ] <= c) & (sc[ly    ][lx + 1] <= c) &
                    (sc[ly    ][lx + 2] <= c) & (sc[ly + 1][lx    ] <= c) &
                    (sc[ly + 1][lx + 2] <= c) & (sc[ly + 2][lx    ] <= c) &
                    (sc[ly + 2][lx + 1] <= c) & (sc[ly + 2][lx + 2] <= c);
        if (keep) {
            uint32_t idx = (uint32_t)(gy * W + gx);
            uint32_t cb  = __float_as_uint(c);   // conf > 0 => monotone bits
            unsigned long long key =
                ((unsigned long long)cb << 32) |
                (unsigned long long)(0xFFFFFFFFu - idx);
            unsigned p = atomicAdd(&s_cnt, 1u);  // LDS atomic: fast
            s_keys[p] = key;
        }
    }
    __syncthreads();

    unsigned cnt = s_cnt;
    if (threadIdx.x == 0 && cnt > 0u)
        s_base = atomicAdd(&counters[counter_base + img], cnt);  // 1/block
    __syncthreads();

    if (cnt > 0u) {
        unsigned base = s_base;
        unsigned long long* dst = cand + (size_t)(counter_base + img) * cap;
        for (unsigned i = threadIdx.x; i < cnt; i += 256) {
            unsigned slot = base + i;
            if (slot < (unsigned)cap) dst[slot] = s_keys[i];  // coalesced
        }
    }
}

// ---------------------------------------------------------------------------
// Kernel 2: per-(map,image) exact top-100 via 8-pass MSB radix select over
// 64-bit keys staged in LDS, then compact + bitonic sort + decode/write.
// ---------------------------------------------------------------------------
__global__ __launch_bounds__(256) void select_kernel(
    const unsigned long long* __restrict__ cand,
    const uint32_t* __restrict__ counters,
    int cap,
    const float* __restrict__ pbbox,   // (64, 4, 68, 120)
    float* __restrict__ out)           // (64, 200, 5)
{
    const int b   = blockIdx.x;   // 0..127
    const int map = b >> 6;       // 0 = player, 1 = ball
    const int img = b & 63;

    __shared__ unsigned long long skeys[CAPMAX];   // 128 KB
    __shared__ unsigned int hist[256];
    __shared__ unsigned long long stop[128];
    __shared__ unsigned int scnt;
    __shared__ unsigned long long s_prefix;
    __shared__ unsigned int s_krem;

    unsigned craw = counters[b];
    int c = (int)(craw < (unsigned)cap ? craw : (unsigned)cap);
    const unsigned long long* my = cand + (size_t)b * cap;

    for (int i = threadIdx.x; i < c; i += 256) skeys[i] = my[i];
    if (threadIdx.x == 0) { s_prefix = 0ull; s_krem = KDET; scnt = 0u; }
    __syncthreads();

    // 8-pass MSB radix select for the KDET-th largest key
    for (int pass = 0; pass < 8; ++pass) {
        int shift = 56 - 8 * pass;
        for (int i = threadIdx.x; i < 256; i += 256) hist[i] = 0u;
        __syncthreads();
        unsigned long long pref = s_prefix;
        for (int i = threadIdx.x; i < c; i += 256) {
            unsigned long long key = skeys[i];
            bool match = (pass == 0) || ((key >> (shift + 8)) == pref);
            if (match) atomicAdd(&hist[(unsigned)(key >> shift) & 255u], 1u);
        }
        __syncthreads();
        if (threadIdx.x == 0) {
            unsigned krem = s_krem;
            unsigned cum = 0; int sel = 0;
            for (int bin = 255; bin >= 0; --bin) {
                unsigned h = hist[bin];
                if (cum + h >= krem) { sel = bin; s_krem = krem - cum; break; }
                cum += h;
            }
            s_prefix = (s_prefix << 8) | (unsigned long long)(unsigned)sel;
        }
        __syncthreads();
    }
    unsigned long long kth = s_prefix;

    // compact keys >= kth; keys are unique (index bits) -> exactly KDET
    for (int i = threadIdx.x; i < c; i += 256) {
        unsigned long long key = skeys[i];
        if (key >= kth) {
            unsigned p = atomicAdd(&scnt, 1u);
            if (p < 128u) stop[p] = key;
        }
    }
    __syncthreads();
    unsigned cnt = scnt;
    for (int i = threadIdx.x; i < 128; i += 256)
        if ((unsigned)i >= cnt) stop[i] = 0ull;

    // bitonic sort ascending, n = 128
    for (int k2 = 2; k2 <= 128; k2 <<= 1) {
        for (int j = k2 >> 1; j > 0; j >>= 1) {
            __syncthreads();
            if (threadIdx.x < 128) {
                int i = threadIdx.x, ixj = i ^ j;
                if (ixj > i) {
                    unsigned long long a = stop[i], bb = stop[ixj];
                    bool up = ((i & k2) == 0);
                    if ((up && a > bb) || (!up && a < bb)) { stop[i] = bb; stop[ixj] = a; }
                }
            }
        }
    }
    __syncthreads();

    // decode + write: rank r takes stop[127 - r] (descending)
    int r = threadIdx.x;
    if (r < KDET) {
        unsigned long long key = stop[127 - r];
        float* o = out + ((size_t)img * 200 + (map ? (100 + r) : r)) * 5;
        if (key == 0ull) {   // cannot happen with this data; safe fallback
            o[0] = 0.f; o[1] = 0.f; o[2] = 0.f; o[3] = 0.f; o[4] = 0.f;
        } else {
            float val = __uint_as_float((unsigned)(key >> 32));  // ref's conf
            unsigned idx = 0xFFFFFFFFu - (unsigned)(key & 0xFFFFFFFFull);

            int W  = map ? 480 : 120;
            float ds   = map ? 4.0f : 16.0f;
            float half = map ? 1.5f : 7.5f;
            int ix = (int)(idx % (unsigned)W), iy = (int)(idx / (unsigned)W);
            float xc = (float)ix * ds + half;
            float yc = (float)iy * ds + half;

            float t0, t1, t2, t3;
            if (map == 0) {
                const float* bb = pbbox + (size_t)img * 4 * 8160;
                t0 = bb[idx]            * 1920.0f;   // w*ds = 120*16
                t1 = bb[8160 + idx]     * 1088.0f;   // h*ds = 68*16
                t2 = bb[2 * 8160 + idx] * 1920.0f;
                t3 = bb[3 * 8160 + idx] * 1088.0f;
            } else {
                t0 = 0.0f; t1 = 0.0f; t2 = 20.0f; t3 = 20.0f;
            }
            float bx = xc + t0, by = yc + t1;
            o[0] = bx - 0.5f * t2;
            o[1] = by - 0.5f * t3;
            o[2] = bx + 0.5f * t2;
            o[3] = by + 0.5f * t3;
            o[4] = val;
        }
    }
}

extern "C" void kernel_launch(void* const* d_in, const int* in_sizes, int n_in,
                              void* d_out, int out_size, void* d_ws, size_t ws_size,
                              hipStream_t stream) {
    const float* pfm = (const float*)d_in[0];  // (64,2,68,120)
    const float* pbb = (const float*)d_in[1];  // (64,4,68,120)
    const float* bfm = (const float*)d_in[2];  // (64,2,272,480)
    float* out = (float*)d_out;                // (64,200,5)

    uint32_t* counters = (uint32_t*)d_ws;                                  // 128 * u32
    unsigned long long* cand = (unsigned long long*)((char*)d_ws + 512);

    int cap = CAPMAX;
    size_t need = 512 + (size_t)128 * (size_t)cap * 8;
    if (ws_size < need) {  // defensive; deterministic across calls
        cap = (int)((ws_size > 512 ? (ws_size - 512) : 0) / (128 * 8));
        if (cap > CAPMAX) cap = CAPMAX;
        if (cap < 1) cap = 1;
    }

    hipMemsetAsync(d_ws, 0, 512, stream);

    {   // player: H=68 W=120
        int tiles_x = (120 + TW - 1) / TW;   // 2
        int tiles_y = (68  + TH - 1) / TH;   // 5
        nms_kernel<<<64 * tiles_x * tiles_y, 256, 0, stream>>>(
            pfm, counters, 0, cand, cap, 68, 120, tiles_x, tiles_y);
    }
    {   // ball: H=272 W=480
        int tiles_x = (480 + TW - 1) / TW;   // 8
        int tiles_y = (272 + TH - 1) / TH;   // 17
        nms_kernel<<<64 * tiles_x * tiles_y, 256, 0, stream>>>(
            bfm, counters, 64, cand, cap, 272, 480, tiles_x, tiles_y);
    }
    select_kernel<<<128, 256, 0, stream>>>(cand, counters, cap, pbb, out);
}

// Round 5
// 235.486 us; speedup vs baseline: 7.0442x; 1.5092x over previous
//
#include <hip/hip_runtime.h>
#include <cstdint>
#include <math.h>

#define TW 64
#define TH 16
#define RGX 18          // float4 groups per staged row (72 cols)
#define RGY (TH + 2)    // staged rows
#define SSTR 73         // LDS row stride (72 + 1 pad)
#define CAPMAX 16384
#define KDET 100

// ---------------------------------------------------------------------------
// Kernel 1: bitwise-faithful f32 softmax conf + 3x3 NMS + block-aggregated
// candidate compaction. Staging is float4-vectorized (16B/lane); per-element
// arithmetic is unchanged, so conf stays bitwise identical to the np ref:
//   t = min-max; u = (float)exp((double)t); s = u+1; conf = (x1>x0)? 1/s : u/s
// Wait -- careful: conf is channel-1 prob: if b>a (x1 is max) conf = 1/s.
// Key = (conf_bits << 32) | (0xFFFFFFFF - index); one global atomic per block.
// ---------------------------------------------------------------------------
__global__ __launch_bounds__(256) void nms_kernel(
    const float* __restrict__ fm,          // (64, 2, H, W)
    uint32_t* __restrict__ counters,       // 128 counters
    int counter_base,
    unsigned long long* __restrict__ cand, // 128 * cap keys
    int cap, int H, int W, int tiles_x, int tiles_y)
{
    const int tpi = tiles_x * tiles_y;
    const int img = blockIdx.x / tpi;
    const int t   = blockIdx.x % tpi;
    const int tx = t % tiles_x, ty = t / tiles_x;

    const size_t hw = (size_t)H * W;
    const float* c0 = fm + (size_t)img * 2 * hw;
    const float* c1 = c0 + hw;

    __shared__ float sc[RGY][SSTR];
    __shared__ unsigned long long s_keys[TH * TW];
    __shared__ unsigned int s_cnt, s_base;

    if (threadIdx.x == 0) s_cnt = 0u;

    const int xs = tx * TW - 4;   // float4-aligned staged col start
    const int ys = ty * TH - 1;   // staged row start

    for (int task = threadIdx.x; task < RGX * RGY; task += 256) {
        const int g = task % RGX, r = task / RGX;
        const int row = ys + r;
        const int col = xs + 4 * g;
        float cf[4];
        if (row >= 0 && row < H && col >= 0 && col + 3 < W) {
            const float* p0 = c0 + (size_t)row * W + col;
            const float* p1 = c1 + (size_t)row * W + col;
            const float4 a4 = *(const float4*)p0;
            const float4 b4 = *(const float4*)p1;
            const float aa[4] = {a4.x, a4.y, a4.z, a4.w};
            const float bb[4] = {b4.x, b4.y, b4.z, b4.w};
            #pragma unroll
            for (int j = 0; j < 4; ++j) {
                float a = aa[j], b = bb[j];
                float tm = (a > b) ? (b - a) : (a - b);   // min - max
                float u  = (float)exp((double)tm);        // correctly-rounded
                float s  = u + 1.0f;
                cf[j] = (a > b) ? (u / s) : (1.0f / s);   // channel-1 prob
            }
        } else if (row >= 0 && row < H) {
            #pragma unroll
            for (int j = 0; j < 4; ++j) {
                const int cj = col + j;
                if (cj >= 0 && cj < W) {
                    float a = c0[(size_t)row * W + cj];
                    float b = c1[(size_t)row * W + cj];
                    float tm = (a > b) ? (b - a) : (a - b);
                    float u  = (float)exp((double)tm);
                    float s  = u + 1.0f;
                    cf[j] = (a > b) ? (u / s) : (1.0f / s);
                } else cf[j] = -INFINITY;
            }
        } else {
            cf[0] = cf[1] = cf[2] = cf[3] = -INFINITY;
        }
        #pragma unroll
        for (int j = 0; j < 4; ++j) sc[r][4 * g + j] = cf[j];
    }
    __syncthreads();

    // interior NMS: thread handles 4 consecutive px
    {
        const int lx = (threadIdx.x & 15) * 4;
        const int ly = threadIdx.x >> 4;
        const int gy = ty * TH + ly;
        if (gy < H) {
            #pragma unroll
            for (int j = 0; j < 4; ++j) {
                const int gx = tx * TW + lx + j;
                if (gx >= W) continue;
                const int cx = lx + 4 + j;   // region col of this px
                const int ry = ly + 1;       // region row of this px
                const float c = sc[ry][cx];
                bool keep =
                    (sc[ry - 1][cx - 1] <= c) & (sc[ry - 1][cx] <= c) &
                    (sc[ry - 1][cx + 1] <= c) & (sc[ry][cx - 1] <= c) &
                    (sc[ry][cx + 1] <= c)     & (sc[ry + 1][cx - 1] <= c) &
                    (sc[ry + 1][cx] <= c)     & (sc[ry + 1][cx + 1] <= c);
                if (keep) {
                    const uint32_t idx = (uint32_t)(gy * W + gx);
                    const uint32_t cb  = __float_as_uint(c);
                    unsigned long long key =
                        ((unsigned long long)cb << 32) |
                        (unsigned long long)(0xFFFFFFFFu - idx);
                    unsigned p = atomicAdd(&s_cnt, 1u);
                    s_keys[p] = key;
                }
            }
        }
    }
    __syncthreads();

    const unsigned cnt = s_cnt;
    if (threadIdx.x == 0 && cnt > 0u)
        s_base = atomicAdd(&counters[counter_base + img], cnt);
    __syncthreads();

    if (cnt > 0u) {
        const unsigned base = s_base;
        unsigned long long* dst = cand + (size_t)(counter_base + img) * cap;
        for (unsigned i = threadIdx.x; i < cnt; i += 256) {
            const unsigned slot = base + i;
            if (slot < (unsigned)cap) dst[slot] = s_keys[i];
        }
    }
}

// ---------------------------------------------------------------------------
// Kernel 2: exact top-100 per (map,image). 4-pass MSB radix select over the
// 32 CONF bits (ties in conf resolved later by the full-key sort), with the
// per-pass bin pick done by a parallel 256-bin suffix-sum (8 LDS steps) —
// the previous serial thread-0 scan was ~100 us of dependent-LDS latency.
// ---------------------------------------------------------------------------
__global__ __launch_bounds__(256) void select_kernel(
    const unsigned long long* __restrict__ cand,
    const uint32_t* __restrict__ counters,
    int cap,
    const float* __restrict__ pbbox,   // (64, 4, 68, 120)
    float* __restrict__ out)           // (64, 200, 5)
{
    const int b   = blockIdx.x;   // 0..127
    const int map = b >> 6;
    const int img = b & 63;
    const int tid = threadIdx.x;

    __shared__ unsigned long long skeys[CAPMAX];   // 128 KB
    __shared__ unsigned int hist[256];
    __shared__ unsigned int sfx[256];
    __shared__ unsigned long long stop[128];
    __shared__ unsigned int scnt;
    __shared__ unsigned int s_pref;     // accumulated conf-bit prefix
    __shared__ unsigned int s_krem, s_krem_next, s_sel;

    const unsigned craw = counters[b];
    const int c = (int)(craw < (unsigned)cap ? craw : (unsigned)cap);
    const unsigned long long* my = cand + (size_t)b * cap;

    for (int i = tid; i < c; i += 256) skeys[i] = my[i];
    if (tid == 0) { s_pref = 0u; s_krem = KDET; scnt = 0u; }
    __syncthreads();

    // 4-pass radix select on conf = key[63:32]
    for (int pass = 0; pass < 4; ++pass) {
        const int shift = 24 - 8 * pass;
        hist[tid] = 0u;
        __syncthreads();
        const unsigned pref = s_pref;
        for (int i = tid; i < c; i += 256) {
            const unsigned conf = (unsigned)(skeys[i] >> 32);
            const bool match = (pass == 0) || ((conf >> (shift + 8)) == pref);
            if (match) atomicAdd(&hist[(conf >> shift) & 255u], 1u);
        }
        __syncthreads();
        // parallel inclusive suffix sum over 256 bins
        sfx[tid] = hist[tid];
        __syncthreads();
        #pragma unroll
        for (int off = 1; off < 256; off <<= 1) {
            const unsigned v = sfx[tid] + ((tid + off < 256) ? sfx[tid + off] : 0u);
            __syncthreads();
            sfx[tid] = v;
            __syncthreads();
        }
        const unsigned krem = s_krem;
        const unsigned above = (tid < 255) ? sfx[tid + 1] : 0u;
        if (sfx[tid] >= krem && above < krem) {
            s_sel = (unsigned)tid;
            s_krem_next = krem - above;
        }
        if (tid == 0 && sfx[0] < krem) {  // degenerate (c < KDET) fallback
            s_sel = 0u;
            s_krem_next = krem;
        }
        __syncthreads();
        if (tid == 0) {
            s_pref = (s_pref << 8) | s_sel;
            s_krem = s_krem_next;
        }
        __syncthreads();
    }
    const unsigned long long kth = ((unsigned long long)s_pref) << 32;

    // compact keys with conf >= cv (count = 100 + (#ties - krem), tiny slack ok)
    for (int i = tid; i < c; i += 256) {
        const unsigned long long key = skeys[i];
        if (key >= kth) {
            const unsigned p = atomicAdd(&scnt, 1u);
            if (p < 128u) stop[p] = key;
        }
    }
    __syncthreads();
    const unsigned cnt = scnt;
    if (tid < 128 && (unsigned)tid >= cnt) stop[tid] = 0ull;

    // bitonic sort ascending, n = 128 (full key: conf desc ties -> idx asc)
    for (int k2 = 2; k2 <= 128; k2 <<= 1) {
        for (int j = k2 >> 1; j > 0; j >>= 1) {
            __syncthreads();
            if (tid < 128) {
                const int i = tid, ixj = i ^ j;
                if (ixj > i) {
                    const unsigned long long a = stop[i], bb2 = stop[ixj];
                    const bool up = ((i & k2) == 0);
                    if ((up && a > bb2) || (!up && a < bb2)) {
                        stop[i] = bb2; stop[ixj] = a;
                    }
                }
            }
        }
    }
    __syncthreads();

    const int r = tid;
    if (r < KDET) {
        const unsigned long long key = stop[127 - r];
        float* o = out + ((size_t)img * 200 + (map ? (100 + r) : r)) * 5;
        if (key == 0ull) {
            o[0] = 0.f; o[1] = 0.f; o[2] = 0.f; o[3] = 0.f; o[4] = 0.f;
        } else {
            const float val = __uint_as_float((unsigned)(key >> 32));
            const unsigned idx = 0xFFFFFFFFu - (unsigned)(key & 0xFFFFFFFFull);

            const int W  = map ? 480 : 120;
            const float ds   = map ? 4.0f : 16.0f;
            const float half = map ? 1.5f : 7.5f;
            const int ix = (int)(idx % (unsigned)W), iy = (int)(idx / (unsigned)W);
            const float xc = (float)ix * ds + half;
            const float yc = (float)iy * ds + half;

            float t0, t1, t2, t3;
            if (map == 0) {
                const float* bbp = pbbox + (size_t)img * 4 * 8160;
                t0 = bbp[idx]            * 1920.0f;
                t1 = bbp[8160 + idx]     * 1088.0f;
                t2 = bbp[2 * 8160 + idx] * 1920.0f;
                t3 = bbp[3 * 8160 + idx] * 1088.0f;
            } else {
                t0 = 0.0f; t1 = 0.0f; t2 = 20.0f; t3 = 20.0f;
            }
            const float bx = xc + t0, by = yc + t1;
            o[0] = bx - 0.5f * t2;
            o[1] = by - 0.5f * t3;
            o[2] = bx + 0.5f * t2;
            o[3] = by + 0.5f * t3;
            o[4] = val;
        }
    }
}

extern "C" void kernel_launch(void* const* d_in, const int* in_sizes, int n_in,
                              void* d_out, int out_size, void* d_ws, size_t ws_size,
                              hipStream_t stream) {
    const float* pfm = (const float*)d_in[0];  // (64,2,68,120)
    const float* pbb = (const float*)d_in[1];  // (64,4,68,120)
    const float* bfm = (const float*)d_in[2];  // (64,2,272,480)
    float* out = (float*)d_out;                // (64,200,5)

    uint32_t* counters = (uint32_t*)d_ws;
    unsigned long long* cand = (unsigned long long*)((char*)d_ws + 512);

    int cap = CAPMAX;
    size_t need = 512 + (size_t)128 * (size_t)cap * 8;
    if (ws_size < need) {
        cap = (int)((ws_size > 512 ? (ws_size - 512) : 0) / (128 * 8));
        if (cap > CAPMAX) cap = CAPMAX;
        if (cap < 1) cap = 1;
    }

    hipMemsetAsync(d_ws, 0, 512, stream);

    {   // player: H=68 W=120
        int tiles_x = (120 + TW - 1) / TW;   // 2
        int tiles_y = (68  + TH - 1) / TH;   // 5
        nms_kernel<<<64 * tiles_x * tiles_y, 256, 0, stream>>>(
            pfm, counters, 0, cand, cap, 68, 120, tiles_x, tiles_y);
    }
    {   // ball: H=272 W=480
        int tiles_x = (480 + TW - 1) / TW;   // 8
        int tiles_y = (272 + TH - 1) / TH;   // 17
        nms_kernel<<<64 * tiles_x * tiles_y, 256, 0, stream>>>(
            bfm, counters, 64, cand, cap, 272, 480, tiles_x, tiles_y);
    }
    select_kernel<<<128, 256, 0, stream>>>(cand, counters, cap, pbb, out);
}